// Round 8
// baseline (133.868 us; speedup 1.0000x reference)
//
#include <hip/hip_runtime.h>
#include <math.h>

typedef unsigned short u16;
typedef unsigned int u32;
typedef __attribute__((ext_vector_type(2))) float f32x2;
typedef __attribute__((ext_vector_type(4))) float f32x4;
typedef __attribute__((ext_vector_type(8))) short bf16x8;

// adjacency-collapse constants: u = 1/(6+1e-8); s = 1+6u; c1=1/s; c2=c1^2; a=u/s; a1c=a*(1+c1)
#define U_CONST   0.16666666638888889f
#define C1_CONST  0.5000000004166667f
#define C2_CONST  0.2500000004166667f
#define A_CONST   0.08333333326388889f
#define A1C_CONST 0.12499999993055555f

__device__ __forceinline__ float bf2f(u16 u){ union{u32 i; float f;} v; v.i=((u32)u)<<16; return v.f; }
__device__ __forceinline__ u16 f2bf(float f){ union{float f; u32 i;} v; v.f=f; u32 x=v.i;
  return (u16)((x + 0x7FFFu + ((x>>16)&1u)) >> 16); }  // RNE (host-prep only path uses this too)

// packed f32 pair -> 2xbf16 in one instr (no builtin on gfx950; RNE)
__device__ __forceinline__ u32 cvtpk(float lo, float hi){
  u32 r; asm("v_cvt_pk_bf16_f32 %0, %1, %2" : "=v"(r) : "v"(lo), "v"(hi)); return r;
}

// fast gelu: erf via A&S 7.1.26 (|err|<=1.5e-7); erf arg is x/sqrt(2)
__device__ __forceinline__ float gelu_f(float x){
  float ax = fabsf(x) * 0.7071067811865476f;
  float t  = __builtin_amdgcn_rcpf(fmaf(0.3275911f, ax, 1.0f));
  float p  = t*fmaf(t, fmaf(t, fmaf(t, fmaf(t, 1.061405429f, -1.453152027f),
                                    1.421413741f), -0.284496736f), 0.254829592f);
  float er = fmaf(-p, __expf(-ax*ax), 1.0f);
  er = copysignf(er, x);
  return 0.5f*x*(1.0f+er);
}
__device__ __forceinline__ float sigmoid_f(float z){
  return __builtin_amdgcn_rcpf(1.0f + __expf(-z));
}

__device__ __forceinline__ bf16x8 pack8(f32x4 a, f32x4 b){
  union { bf16x8 v; u32 w[4]; } r;
  r.w[0]=cvtpk(a[0],a[1]); r.w[1]=cvtpk(a[2],a[3]);
  r.w[2]=cvtpk(b[0],b[1]); r.w[3]=cvtpk(b[2],b[3]);
  return r.v;
}

// in-wave LayerNorm over 128 cols: lane holds col (n<<4)+cl, rows cq*4+j (16-lane shfl reduce)
template<bool GELU>
__device__ __forceinline__ void ln_rows(f32x4 (&acc)[8], const float* __restrict__ gvec,
                                        const float* __restrict__ bvec, int cl){
  float sm[4]={0,0,0,0}, sq[4]={0,0,0,0};
  #pragma unroll
  for (int n=0;n<8;n++)
    #pragma unroll
    for (int j=0;j<4;j++){ float x = acc[n][j]; sm[j]+=x; sq[j]+=x*x; }
  #pragma unroll
  for (int j=0;j<4;j++){
    #pragma unroll
    for (int off=1; off<16; off<<=1){ sm[j]+=__shfl_xor(sm[j],off); sq[j]+=__shfl_xor(sq[j],off); }
    float m = sm[j]*0.0078125f;
    float r = rsqrtf(sq[j]*0.0078125f - m*m + 1e-5f);
    sm[j]=m; sq[j]=r;
  }
  #pragma unroll
  for (int n=0;n<8;n++){
    float gg = gvec[(n<<4)+cl], be = bvec[(n<<4)+cl];
    #pragma unroll
    for (int j=0;j<4;j++){
      float y = (acc[n][j]-sm[j])*sq[j]*gg + be;
      acc[n][j] = GELU ? gelu_f(y) : y;
    }
  }
}

__device__ __forceinline__ void add_vec(f32x4 (&acc)[8], const float* __restrict__ v, int cl){
  #pragma unroll
  for (int n=0;n<8;n++){ float bv = v[(n<<4)+cl];
    #pragma unroll
    for (int j=0;j<4;j++) acc[n][j]+=bv; }
}

// wave-private group sums over rows (rows 0-5 -> s0, 6-11 -> s1), cross-cq shfl
__device__ __forceinline__ void gsum(const f32x4 (&acc)[8], float (&s0)[8], float (&s1)[8], int cq){
  #pragma unroll
  for (int n=0;n<8;n++){
    float a=0.f, b=0.f;
    #pragma unroll
    for (int j=0;j<4;j++){
      int row = (cq<<2)+j;
      float y = acc[n][j];
      a += (row<6)? y : 0.f;
      b += (row>=6 && row<12)? y : 0.f;
    }
    a += __shfl_xor(a,16); a += __shfl_xor(a,32);
    b += __shfl_xor(b,16); b += __shfl_xor(b,32);
    s0[n]=a; s1[n]=b;
  }
}

// store rows 0..11 to global f32 + wave-private LDS A tile (bf16, XOR-swizzled)
__device__ __forceinline__ void spill(const f32x4 (&acc)[8], float* __restrict__ gdst,
                                      char* Al, int cl, int cq){
  #pragma unroll
  for (int n=0;n<8;n++)
    #pragma unroll
    for (int j=0;j<4;j++){
      int R=(cq<<2)+j;
      float y=acc[n][j], yo=__shfl_xor(y,1);
      if (R<12 && !(cl&1)){
        int col=(n<<4)+cl;
        *(f32x2*)(gdst + (size_t)R*128 + col) = (f32x2){y,yo};
        *(u32*)(Al + (R<<8) + ((col<<1) ^ ((R&7)<<4))) = cvtpk(y,yo);
      }
    }
}

// group sums -> wave-private S tile [2][128] bf16 (unswizzled; reads are broadcasts)
__device__ __forceinline__ void ssave(const f32x4 (&acc)[8], char* Sl, int cl, int cq){
  float s0[8], s1[8];
  gsum(acc, s0, s1, cq);
  #pragma unroll
  for (int n=0;n<8;n++){
    float a_ = __shfl_xor(s0[n],1), b_ = __shfl_xor(s1[n],1);
    if (cq==0 && !(cl&1)){
      int col=(n<<4)+cl;
      *(u32*)(Sl + (col<<1))       = cvtpk(s0[n], a_);
      *(u32*)(Sl + 256 + (col<<1)) = cvtpk(s1[n], b_);
    }
  }
}

// K=256 GEMM with 2-deep B prefetch: A = [tile | S_broadcast] wave-private LDS,
// B = interleaved [W|W'] table (stride 256 u16) streamed from global/L2.
__device__ __forceinline__ void gemm256(const u16* __restrict__ WB, const char* Al, const char* Sl,
                                        int rl, int grp, int cl, int cq, f32x4 (&acc)[8]){
  const u16* wb = WB + (cl<<8) + (cq<<3);
  const int swz = (rl&7)<<4;
  bf16x8 Ba[8], Bb[8], aA, aB;
  #pragma unroll
  for (int n=0;n<8;n++) acc[n]=(f32x4){0,0,0,0};
  #pragma unroll
  for (int n=0;n<8;n++) Ba[n] = *(const bf16x8*)(wb + (n<<12));
  #pragma unroll
  for (int n=0;n<8;n++) Bb[n] = *(const bf16x8*)(wb + (n<<12) + 32);
  aA = *(const bf16x8*)(Al + (rl<<8) + (((cq<<4)) ^ swz));
  aB = *(const bf16x8*)(Al + (rl<<8) + ((64+(cq<<4)) ^ swz));
  #pragma unroll
  for (int kt=0; kt<8; kt++){
    if ((kt&1)==0){
      #pragma unroll
      for (int n=0;n<8;n++) acc[n]=__builtin_amdgcn_mfma_f32_16x16x32_bf16(aA, Ba[n], acc[n],0,0,0);
      if (kt+2<8){
        #pragma unroll
        for (int n=0;n<8;n++) Ba[n] = *(const bf16x8*)(wb + (n<<12) + ((kt+2)<<5));
        aA = (kt+2<4) ? *(const bf16x8*)(Al + (rl<<8) + ((((kt+2)<<6)+(cq<<4)) ^ swz))
                      : *(const bf16x8*)(Sl + (grp<<8) + ((kt-2)<<6) + (cq<<4));
      }
    } else {
      #pragma unroll
      for (int n=0;n<8;n++) acc[n]=__builtin_amdgcn_mfma_f32_16x16x32_bf16(aB, Bb[n], acc[n],0,0,0);
      if (kt+2<8){
        #pragma unroll
        for (int n=0;n<8;n++) Bb[n] = *(const bf16x8*)(wb + (n<<12) + ((kt+2)<<5));
        aB = (kt+2<4) ? *(const bf16x8*)(Al + (rl<<8) + ((((kt+2)<<6)+(cq<<4)) ^ swz))
                      : *(const bf16x8*)(Sl + (grp<<8) + ((kt-2)<<6) + (cq<<4));
      }
    }
  }
}

// ---------- prep: bf16 W^T tables. W1T[128][128] at 0; WB2[col][256]=[Wx|Wsv] at 16384;
//            WB3[col][256]=[sW1a | u*sW1b] at 49152 ----------
__global__ void k_prep(const float* __restrict__ W1, const float* __restrict__ chw,
                       const float* __restrict__ sW1, u16* __restrict__ WT5){
  int i = blockIdx.x*256 + threadIdx.x;          // i = f*128+h
  int f = i>>7, h = i&127;
  float w0 = chw[i], w1 = chw[16384+i], w2 = chw[32768+i];
  WT5[(h<<7)+f]                 = f2bf(W1[i]);
  WT5[16384 + (h<<8) + f]       = f2bf(w0 + C1_CONST*w1 + C2_CONST*w2);
  WT5[16384 + (h<<8) + 128 + f] = f2bf(A_CONST*w1 + A1C_CONST*w2);
  WT5[49152 + (h<<8) + f]       = f2bf(sW1[i]);
  WT5[49152 + (h<<8) + 128 + f] = f2bf(U_CONST*sW1[16384+i]);
}

// ---------- fully fused pipeline: zero barriers, wave = 2 groups (12 rows) end-to-end ----------
__global__ __launch_bounds__(256, 4)
void k_all(const float* __restrict__ X_de, const u16* __restrict__ WT5,
           const float* __restrict__ b1, const float* __restrict__ ln1g, const float* __restrict__ ln1b,
           const float* __restrict__ chb, const float* __restrict__ clng, const float* __restrict__ clnb,
           const float* __restrict__ sb1, const float* __restrict__ slng, const float* __restrict__ slnb,
           const float* __restrict__ sW2, const float* __restrict__ sb2p,
           float* __restrict__ out)
{
  __shared__ __align__(16) char lds[4][3584];   // per wave: A tile 12x256B + S tile 512B
  const int tid=threadIdx.x, w=tid>>6, lane=tid&63, cl=lane&15, cq=lane>>4;
  char* Al = lds[w];
  char* Sl = lds[w] + 3072;
  const int wid = blockIdx.x*4 + w;
  const int R0 = wid*12, g0 = wid*2;
  const int rl = (cl<12)? cl : 0;
  const int grp = (rl>=6)? 1 : 0;

  // adj output: constant (LN over size-1 axis == aln_b -> softmax uniform). 288 elems/block.
  {
    float* adj = out + 1048576;
    #pragma unroll
    for (int k=0;k<2;k++){ int idx = tid + (k<<8); if (idx < 288) adj[(size_t)blockIdx.x*288 + idx] = 0.16666667f; }
  }

  // ---- stage 1: Xn = gelu(LN(X@W1 + b1)) ; A direct from global, B batched per K-step ----
  int grow = R0 + rl;
  u32 grp6 = ((u32)grow * 43691u) >> 18;         // grow/6 (exact in range)
  int c = grow - (int)grp6*6;
  const float* xrow = X_de + (((size_t)(((int)(grp6>>7))*6 + c)<<7) + (int)(grp6&127))*128 + (cq<<3);
  f32x4 acc[8];
  bf16x8 af[4];
  #pragma unroll
  for (int kt=0;kt<4;kt++){
    f32x4 lo = *(const f32x4*)(xrow + (kt<<5));
    f32x4 hi = *(const f32x4*)(xrow + (kt<<5)+4);
    af[kt] = pack8(lo,hi);
  }
  #pragma unroll
  for (int n=0;n<8;n++) acc[n]=(f32x4){0,0,0,0};
  {
    const u16* wb1 = WT5 + (cl<<7) + (cq<<3);
    bf16x8 Ba[8];
    #pragma unroll
    for (int kt=0;kt<4;kt++){
      #pragma unroll
      for (int n=0;n<8;n++) Ba[n] = *(const bf16x8*)(wb1 + (n<<11) + (kt<<5));
      #pragma unroll
      for (int n=0;n<8;n++)
        acc[n] = __builtin_amdgcn_mfma_f32_16x16x32_bf16(af[kt], Ba[n], acc[n],0,0,0);
    }
  }
  add_vec(acc, b1, cl);
  ln_rows<true>(acc, ln1g, ln1b, cl);
  spill(acc, out + 1343488 + (size_t)R0*128, Al, cl, cq);   // Xn out + LDS chain
  ssave(acc, Sl, cl, cq);                                   // S

  // ---- stage 2: g = LN(Xn@Wx + S@Wsv + chb) (K=256 fused, T2 eliminated) ----
  gemm256(WT5+16384, Al, Sl, rl, grp, cl, cq, acc);
  add_vec(acc, chb, cl);
  ln_rows<false>(acc, clng, clnb, cl);
  spill(acc, out + 7634944 + (size_t)R0*128, Al, cl, cq);   // g out + LDS chain
  ssave(acc, Sl, cl, cq);                                   // Sg

  // ---- stage 3: h = gelu(LN(g@sW1a + Sg@(u*sW1b) + sb1)) ; att; epoch ----
  gemm256(WT5+49152, Al, Sl, rl, grp, cl, cq, acc);
  add_vec(acc, sb1, cl);
  ln_rows<true>(acc, slng, slnb, cl);

  float z0=0,z1=0,z2=0,z3=0;
  #pragma unroll
  for (int n=0;n<8;n++){
    float wv = sW2[(n<<4)+cl];
    z0 = fmaf(acc[n][0], wv, z0); z1 = fmaf(acc[n][1], wv, z1);
    z2 = fmaf(acc[n][2], wv, z2); z3 = fmaf(acc[n][3], wv, z3);
  }
  #pragma unroll
  for (int off=1; off<16; off<<=1){
    z0 += __shfl_xor(z0,off); z1 += __shfl_xor(z1,off);
    z2 += __shfl_xor(z2,off); z3 += __shfl_xor(z3,off);
  }
  float s2 = sb2p[0];
  float a0 = sigmoid_f(z0+s2), a1 = sigmoid_f(z1+s2), a2 = sigmoid_f(z2+s2), a3 = sigmoid_f(z3+s2);

  float attr[12];
  #pragma unroll
  for (int r=0;r<12;r++){
    int src = (r>>2)<<4;
    float v = (r&3)==0 ? a0 : (r&3)==1 ? a1 : (r&3)==2 ? a2 : a3;
    attr[r] = __shfl(v, src);
  }
  // epoch: weighted mean over 6 node rows, g read back from wave-private LDS (bf16)
  const int c2 = lane<<1;
  #pragma unroll
  for (int gi=0; gi<2; ++gi){
    float ex=0.f, ey=0.f;
    #pragma unroll
    for (int i=0;i<6;i++){
      int r = gi*6+i;
      u32 p = *(const u32*)(Al + (r<<8) + ((c2<<1) ^ ((r&7)<<4)));
      ex = fmaf(attr[r], bf2f((u16)(p&0xFFFFu)), ex);
      ey = fmaf(attr[r], bf2f((u16)(p>>16)), ey);
    }
    *(f32x2*)(out + (size_t)(g0+gi)*128 + c2) = (f32x2){ex*(1.0f/6.0f), ey*(1.0f/6.0f)};
  }
}

// ---------- launcher ----------
extern "C" void kernel_launch(void* const* d_in, const int* in_sizes, int n_in,
                              void* d_out, int out_size, void* d_ws, size_t ws_size,
                              hipStream_t stream){
  const float* X_de = (const float*)d_in[0];
  const float* W1   = (const float*)d_in[1];
  const float* b1   = (const float*)d_in[2];
  const float* ln1g = (const float*)d_in[3];
  const float* ln1b = (const float*)d_in[4];
  // d_in[5..8] (aw, ab, aln_g, aln_b) mathematically dead: LN over size-1 axis == aln_b
  const float* chw  = (const float*)d_in[9];
  const float* chb  = (const float*)d_in[10];
  const float* clng = (const float*)d_in[11];
  const float* clnb = (const float*)d_in[12];
  const float* sW1  = (const float*)d_in[13];
  const float* sb1  = (const float*)d_in[14];
  const float* slng = (const float*)d_in[15];
  const float* slnb = (const float*)d_in[16];
  const float* sW2  = (const float*)d_in[17];
  const float* sb2  = (const float*)d_in[18];

  float* out = (float*)d_out;
  u16* WT5 = (u16*)d_ws;   // 160KB: W1T 32KB + WB2 64KB + WB3 64KB

  hipLaunchKernelGGL(k_prep, dim3(64),   dim3(256), 0, stream, W1, chw, sW1, WT5);
  hipLaunchKernelGGL(k_all,  dim3(1024), dim3(256), 0, stream,
                     X_de, WT5, b1, ln1g, ln1b, chb, clng, clnb,
                     sb1, slng, slnb, sW2, sb2, out);
}

// Round 9
// 53.960 us; speedup vs baseline: 2.4809x; 2.4809x over previous
//
#include <hip/hip_runtime.h>
#include <math.h>

typedef unsigned short u16;
typedef unsigned int u32;
typedef __attribute__((ext_vector_type(2))) float f32x2;
typedef __attribute__((ext_vector_type(4))) float f32x4;
typedef __attribute__((ext_vector_type(8))) short bf16x8;
typedef __attribute__((ext_vector_type(4))) u32 u32x4;

// adjacency-collapse constants: u = 1/(6+1e-8); s = 1+6u; c1=1/s; c2=c1^2; a=u/s; a1c=a*(1+c1)
#define U_CONST   0.16666666638888889f
#define C1_CONST  0.5000000004166667f
#define C2_CONST  0.2500000004166667f
#define A_CONST   0.08333333326388889f
#define A1C_CONST 0.12499999993055555f

__device__ __forceinline__ float bf2f(u16 u){ union{u32 i; float f;} v; v.i=((u32)u)<<16; return v.f; }
__device__ __forceinline__ u16 f2bf(float f){ union{float f; u32 i;} v; v.f=f; u32 x=v.i;
  return (u16)((x + 0x7FFFu + ((x>>16)&1u)) >> 16); }  // RNE

// packed f32 pair -> 2xbf16 (RNE), one instr
__device__ __forceinline__ u32 cvtpk(float lo, float hi){
  u32 r; asm("v_cvt_pk_bf16_f32 %0, %1, %2" : "=v"(r) : "v"(lo), "v"(hi)); return r;
}

// fast gelu: erf via A&S 7.1.26 (|err|<=1.5e-7); erf arg is x/sqrt(2)
__device__ __forceinline__ float gelu_f(float x){
  float ax = fabsf(x) * 0.7071067811865476f;
  float t  = __builtin_amdgcn_rcpf(fmaf(0.3275911f, ax, 1.0f));
  float p  = t*fmaf(t, fmaf(t, fmaf(t, fmaf(t, 1.061405429f, -1.453152027f),
                                    1.421413741f), -0.284496736f), 0.254829592f);
  float er = fmaf(-p, __expf(-ax*ax), 1.0f);
  er = copysignf(er, x);
  return 0.5f*x*(1.0f+er);
}
__device__ __forceinline__ float sigmoid_f(float z){
  return __builtin_amdgcn_rcpf(1.0f + __expf(-z));
}

__device__ __forceinline__ bf16x8 pack8(f32x4 a, f32x4 b){
  union { bf16x8 v; u32 w[4]; } r;
  r.w[0]=cvtpk(a[0],a[1]); r.w[1]=cvtpk(a[2],a[3]);
  r.w[2]=cvtpk(b[0],b[1]); r.w[3]=cvtpk(b[2],b[3]);
  return r.v;
}

// in-wave LayerNorm over 128 cols: lane holds col (n<<4)+cl, rows cq*4+j (16-lane shfl reduce)
template<bool GELU>
__device__ __forceinline__ void ln_rows(f32x4 (&acc)[8], const float* __restrict__ gvec,
                                        const float* __restrict__ bvec, int cl){
  float sm[4]={0,0,0,0}, sq[4]={0,0,0,0};
  #pragma unroll
  for (int n=0;n<8;n++)
    #pragma unroll
    for (int j=0;j<4;j++){ float x = acc[n][j]; sm[j]+=x; sq[j]+=x*x; }
  #pragma unroll
  for (int j=0;j<4;j++){
    #pragma unroll
    for (int off=1; off<16; off<<=1){ sm[j]+=__shfl_xor(sm[j],off); sq[j]+=__shfl_xor(sq[j],off); }
    float m = sm[j]*0.0078125f;
    float r = rsqrtf(sq[j]*0.0078125f - m*m + 1e-5f);
    sm[j]=m; sq[j]=r;
  }
  #pragma unroll
  for (int n=0;n<8;n++){
    float gg = gvec[(n<<4)+cl], be = bvec[(n<<4)+cl];
    #pragma unroll
    for (int j=0;j<4;j++){
      float y = (acc[n][j]-sm[j])*sq[j]*gg + be;
      acc[n][j] = GELU ? gelu_f(y) : y;
    }
  }
}

__device__ __forceinline__ void add_vec(f32x4 (&acc)[8], const float* __restrict__ v, int cl){
  #pragma unroll
  for (int n=0;n<8;n++){ float bv = v[(n<<4)+cl];
    #pragma unroll
    for (int j=0;j<4;j++) acc[n][j]+=bv; }
}

// wave-private group sums over rows (rows 0-5 -> s0, 6-11 -> s1), cross-cq shfl
__device__ __forceinline__ void gsum(const f32x4 (&acc)[8], float (&s0)[8], float (&s1)[8], int cq){
  #pragma unroll
  for (int n=0;n<8;n++){
    float a=0.f, b=0.f;
    #pragma unroll
    for (int j=0;j<4;j++){
      int row = (cq<<2)+j;
      float y = acc[n][j];
      a += (row<6)? y : 0.f;
      b += (row>=6 && row<12)? y : 0.f;
    }
    a += __shfl_xor(a,16); a += __shfl_xor(a,32);
    b += __shfl_xor(b,16); b += __shfl_xor(b,32);
    s0[n]=a; s1[n]=b;
  }
}

// store rows 0..11 to global f32 + wave-private LDS A tile (bf16, XOR-swizzled)
__device__ __forceinline__ void spill(const f32x4 (&acc)[8], float* __restrict__ gdst,
                                      char* Al, int cl, int cq){
  #pragma unroll
  for (int n=0;n<8;n++)
    #pragma unroll
    for (int j=0;j<4;j++){
      int R=(cq<<2)+j;
      float y=acc[n][j], yo=__shfl_xor(y,1);
      if (R<12 && !(cl&1)){
        int col=(n<<4)+cl;
        *(f32x2*)(gdst + (size_t)R*128 + col) = (f32x2){y,yo};
        *(u32*)(Al + (R<<8) + ((col<<1) ^ ((R&7)<<4))) = cvtpk(y,yo);
      }
    }
}

// group sums -> wave-private S tile [2][128] bf16 (unswizzled; reads are broadcasts)
__device__ __forceinline__ void ssave(const f32x4 (&acc)[8], char* Sl, int cl, int cq){
  float s0[8], s1[8];
  gsum(acc, s0, s1, cq);
  #pragma unroll
  for (int n=0;n<8;n++){
    float a_ = __shfl_xor(s0[n],1), b_ = __shfl_xor(s1[n],1);
    if (cq==0 && !(cl&1)){
      int col=(n<<4)+cl;
      *(u32*)(Sl + (col<<1))       = cvtpk(s0[n], a_);
      *(u32*)(Sl + 256 + (col<<1)) = cvtpk(s1[n], b_);
    }
  }
}

// ---------- block-shared W staging (32KB, XOR-swizzled) + fragment accessors ----------
__device__ __forceinline__ void stageW(u16* Wb, const u16* __restrict__ slot, int tid){
  const u32x4* src = (const u32x4*)slot;          // 2048 x 16B
  #pragma unroll
  for (int it=0; it<4; ++it){
    int i = tid + (it<<9);                        // 512 threads x 4
    int h = i >> 4, s = i & 15;
    u32x4 v = src[i];
    *(u32x4*)((char*)Wb + (h<<8) + ((s ^ (h&7))<<4)) = v;
  }
}
__device__ __forceinline__ bf16x8 bfrag(const u16* Wb, int col, int kt, int cq){
  int s = (kt<<2) + cq;
  return *(const bf16x8*)((const char*)Wb + (col<<8) + ((s ^ (col&7))<<4));
}
__device__ __forceinline__ bf16x8 afrag(const char* Al, int rl, int kt, int cq){
  return *(const bf16x8*)(Al + (rl<<8) + (((kt<<6)+(cq<<4)) ^ ((rl&7)<<4)));
}

// K=128 half-GEMM: A from wave-private Al tile, B from staged Wb
template<bool INIT>
__device__ __forceinline__ void gemm_a(const u16* Wb, const char* Al, int rl, int cl, int cq,
                                       f32x4 (&acc)[8]){
  if (INIT){
    #pragma unroll
    for (int n=0;n<8;n++) acc[n]=(f32x4){0,0,0,0};
  }
  #pragma unroll
  for (int kt=0;kt<4;kt++){
    bf16x8 a = afrag(Al, rl, kt, cq);
    #pragma unroll
    for (int n=0;n<8;n++)
      acc[n] = __builtin_amdgcn_mfma_f32_16x16x32_bf16(a, bfrag(Wb,(n<<4)+cl,kt,cq), acc[n],0,0,0);
  }
}
// K=128 half-GEMM: A = group-sum row broadcast from Sl, B from staged Wb (accumulates)
__device__ __forceinline__ void gemm_s(const u16* Wb, const char* Sl, int grp, int cl, int cq,
                                       f32x4 (&acc)[8]){
  #pragma unroll
  for (int kt=0;kt<4;kt++){
    bf16x8 a = *(const bf16x8*)(Sl + (grp<<8) + (kt<<6) + (cq<<4));
    #pragma unroll
    for (int n=0;n<8;n++)
      acc[n] = __builtin_amdgcn_mfma_f32_16x16x32_bf16(a, bfrag(Wb,(n<<4)+cl,kt,cq), acc[n],0,0,0);
  }
}

// ---------- prep: 5 bf16 W^T slots [col h][k f], stride 128 ----------
// u16 offsets: 0:W1T  16384:WxT  32768:WsvT  49152:sW1aT  65536:(u*sW1b)T
__global__ void k_prep(const float* __restrict__ W1, const float* __restrict__ chw,
                       const float* __restrict__ sW1, u16* __restrict__ WT5){
  int i = blockIdx.x*256 + threadIdx.x;          // i = f*128+h
  int dst = ((i&127)<<7) + (i>>7);               // h*128+f
  float w0 = chw[i], w1 = chw[16384+i], w2 = chw[32768+i];
  WT5[dst]         = f2bf(W1[i]);
  WT5[16384+dst]   = f2bf(w0 + C1_CONST*w1 + C2_CONST*w2);
  WT5[32768+dst]   = f2bf(A_CONST*w1 + A1C_CONST*w2);
  WT5[49152+dst]   = f2bf(sW1[i]);
  WT5[65536+dst]   = f2bf(U_CONST*sW1[16384+i]);
}

// ---------- fused pipeline: 8 waves/block, wave = 2 groups (12 rows) end-to-end ----------
__global__ __launch_bounds__(512, 4)
void k_all(const float* __restrict__ X_de, const u16* __restrict__ WT5,
           const float* __restrict__ b1, const float* __restrict__ ln1g, const float* __restrict__ ln1b,
           const float* __restrict__ chb, const float* __restrict__ clng, const float* __restrict__ clnb,
           const float* __restrict__ sb1, const float* __restrict__ slng, const float* __restrict__ slnb,
           const float* __restrict__ sW2, const float* __restrict__ sb2p,
           float* __restrict__ out)
{
  __shared__ __align__(16) u16  Wb[128*128];     // 32KB staged weight (swizzled)
  __shared__ __align__(16) char lds[8][3584];    // per wave: A tile 12x256B + S tile 512B
  const int tid=threadIdx.x, w=tid>>6, lane=tid&63, cl=lane&15, cq=lane>>4;
  char* Al = lds[w];
  char* Sl = lds[w] + 3072;
  const int wid = blockIdx.x*8 + w;
  const int R0 = wid*12, g0 = wid*2;
  const int rl = (cl<12)? cl : 0;
  const int grp = (rl>=6)? 1 : 0;

  // adj output: constant (LN over size-1 axis == aln_b -> softmax uniform). 576/block.
  {
    float* adj = out + 1048576;
    #pragma unroll
    for (int k=0;k<2;k++){ int idx = tid + (k<<9); if (idx < 576) adj[(size_t)blockIdx.x*576 + idx] = 0.16666667f; }
  }

  // stage-1 A preload (in flight during W1T staging)
  int grow = R0 + rl;
  u32 grp6 = ((u32)grow * 43691u) >> 18;         // grow/6 (exact in range)
  int c = grow - (int)grp6*6;
  const float* xrow = X_de + (((size_t)(((int)(grp6>>7))*6 + c)<<7) + (int)(grp6&127))*128 + (cq<<3);
  f32x4 xlo0 = *(const f32x4*)(xrow);
  f32x4 xhi0 = *(const f32x4*)(xrow+4);
  f32x4 xlo1 = *(const f32x4*)(xrow+32);
  f32x4 xhi1 = *(const f32x4*)(xrow+36);
  f32x4 xlo2 = *(const f32x4*)(xrow+64);
  f32x4 xhi2 = *(const f32x4*)(xrow+68);
  f32x4 xlo3 = *(const f32x4*)(xrow+96);
  f32x4 xhi3 = *(const f32x4*)(xrow+100);
  stageW(Wb, WT5, tid);                          // W1T
  bf16x8 af0 = pack8(xlo0,xhi0), af1 = pack8(xlo1,xhi1), af2 = pack8(xlo2,xhi2), af3 = pack8(xlo3,xhi3);
  __syncthreads();

  // ---- stage 1: Xn = gelu(LN(X@W1 + b1)) ----
  f32x4 acc[8];
  #pragma unroll
  for (int n=0;n<8;n++) acc[n]=(f32x4){0,0,0,0};
  #pragma unroll
  for (int n=0;n<8;n++) acc[n]=__builtin_amdgcn_mfma_f32_16x16x32_bf16(af0, bfrag(Wb,(n<<4)+cl,0,cq), acc[n],0,0,0);
  #pragma unroll
  for (int n=0;n<8;n++) acc[n]=__builtin_amdgcn_mfma_f32_16x16x32_bf16(af1, bfrag(Wb,(n<<4)+cl,1,cq), acc[n],0,0,0);
  #pragma unroll
  for (int n=0;n<8;n++) acc[n]=__builtin_amdgcn_mfma_f32_16x16x32_bf16(af2, bfrag(Wb,(n<<4)+cl,2,cq), acc[n],0,0,0);
  #pragma unroll
  for (int n=0;n<8;n++) acc[n]=__builtin_amdgcn_mfma_f32_16x16x32_bf16(af3, bfrag(Wb,(n<<4)+cl,3,cq), acc[n],0,0,0);
  add_vec(acc, b1, cl);
  ln_rows<true>(acc, ln1g, ln1b, cl);
  spill(acc, out + 1343488 + (size_t)R0*128, Al, cl, cq);   // Xn + LDS chain
  ssave(acc, Sl, cl, cq);                                   // S
  __syncthreads();                                          // Wb free

  // ---- stage 2: g = LN(Xn@Wx + S@Wsv + chb) ----
  stageW(Wb, WT5+16384, tid);                               // WxT
  __syncthreads();
  gemm_a<true>(Wb, Al, rl, cl, cq, acc);
  __syncthreads();
  stageW(Wb, WT5+32768, tid);                               // WsvT
  __syncthreads();
  gemm_s(Wb, Sl, grp, cl, cq, acc);
  add_vec(acc, chb, cl);
  ln_rows<false>(acc, clng, clnb, cl);
  spill(acc, out + 7634944 + (size_t)R0*128, Al, cl, cq);   // g + LDS chain
  ssave(acc, Sl, cl, cq);                                   // Sg
  __syncthreads();

  // ---- stage 3: h = gelu(LN(g@sW1a + Sg@(u*sW1b) + sb1)); att; epoch ----
  stageW(Wb, WT5+49152, tid);                               // sW1aT
  __syncthreads();
  gemm_a<true>(Wb, Al, rl, cl, cq, acc);
  __syncthreads();
  stageW(Wb, WT5+65536, tid);                               // (u*sW1b)T
  __syncthreads();
  gemm_s(Wb, Sl, grp, cl, cq, acc);
  add_vec(acc, sb1, cl);
  ln_rows<true>(acc, slng, slnb, cl);

  float z0=0,z1=0,z2=0,z3=0;
  #pragma unroll
  for (int n=0;n<8;n++){
    float wv = sW2[(n<<4)+cl];
    z0 = fmaf(acc[n][0], wv, z0); z1 = fmaf(acc[n][1], wv, z1);
    z2 = fmaf(acc[n][2], wv, z2); z3 = fmaf(acc[n][3], wv, z3);
  }
  #pragma unroll
  for (int off=1; off<16; off<<=1){
    z0 += __shfl_xor(z0,off); z1 += __shfl_xor(z1,off);
    z2 += __shfl_xor(z2,off); z3 += __shfl_xor(z3,off);
  }
  float s2 = sb2p[0];
  float a0 = sigmoid_f(z0+s2), a1 = sigmoid_f(z1+s2), a2 = sigmoid_f(z2+s2), a3 = sigmoid_f(z3+s2);

  float attr[12];
  #pragma unroll
  for (int r=0;r<12;r++){
    int src = (r>>2)<<4;
    float v = (r&3)==0 ? a0 : (r&3)==1 ? a1 : (r&3)==2 ? a2 : a3;
    attr[r] = __shfl(v, src);
  }
  // epoch: weighted mean over 6 node rows, g read from wave-private LDS (bf16)
  const int c2 = lane<<1;
  #pragma unroll
  for (int gi=0; gi<2; ++gi){
    float ex=0.f, ey=0.f;
    #pragma unroll
    for (int i=0;i<6;i++){
      int r = gi*6+i;
      u32 p = *(const u32*)(Al + (r<<8) + ((c2<<1) ^ ((r&7)<<4)));
      ex = fmaf(attr[r], bf2f((u16)(p&0xFFFFu)), ex);
      ey = fmaf(attr[r], bf2f((u16)(p>>16)), ey);
    }
    *(f32x2*)(out + (size_t)(g0+gi)*128 + c2) = (f32x2){ex*(1.0f/6.0f), ey*(1.0f/6.0f)};
  }
}

// ---------- launcher ----------
extern "C" void kernel_launch(void* const* d_in, const int* in_sizes, int n_in,
                              void* d_out, int out_size, void* d_ws, size_t ws_size,
                              hipStream_t stream){
  const float* X_de = (const float*)d_in[0];
  const float* W1   = (const float*)d_in[1];
  const float* b1   = (const float*)d_in[2];
  const float* ln1g = (const float*)d_in[3];
  const float* ln1b = (const float*)d_in[4];
  // d_in[5..8] (aw, ab, aln_g, aln_b) mathematically dead: LN over size-1 axis == aln_b
  const float* chw  = (const float*)d_in[9];
  const float* chb  = (const float*)d_in[10];
  const float* clng = (const float*)d_in[11];
  const float* clnb = (const float*)d_in[12];
  const float* sW1  = (const float*)d_in[13];
  const float* sb1  = (const float*)d_in[14];
  const float* slng = (const float*)d_in[15];
  const float* slnb = (const float*)d_in[16];
  const float* sW2  = (const float*)d_in[17];
  const float* sb2  = (const float*)d_in[18];

  float* out = (float*)d_out;
  u16* WT5 = (u16*)d_ws;   // 160KB: 5 x 32KB bf16 W^T slots

  hipLaunchKernelGGL(k_prep, dim3(64),  dim3(256), 0, stream, W1, chw, sW1, WT5);
  hipLaunchKernelGGL(k_all,  dim3(512), dim3(512), 0, stream,
                     X_de, WT5, b1, ln1g, ln1b, chb, clng, clnb,
                     sb1, slng, slnb, sW2, sb2, out);
}